// Round 4
// baseline (1025.838 us; speedup 1.0000x reference)
//
#include <hip/hip_runtime.h>

typedef __bf16 bf16x8 __attribute__((ext_vector_type(8)));
typedef __bf16 bf16x4 __attribute__((ext_vector_type(4)));
typedef float f32x4 __attribute__((ext_vector_type(4)));
typedef float f32x16 __attribute__((ext_vector_type(16)));

#define MFMA16(a, b, c) __builtin_amdgcn_mfma_f32_16x16x32_bf16((a), (b), (c), 0, 0, 0)
#define MFMA32(a, b, c) __builtin_amdgcn_mfma_f32_32x32x16_bf16((a), (b), (c), 0, 0, 0)

static constexpr int SEQ = 4096;
static constexpr int DIM = 512;

typedef __attribute__((address_space(3))) void lds_void;
typedef __attribute__((address_space(1))) const void gbl_void;

__device__ __forceinline__ void glds16(const void* g, void* l) {
    __builtin_amdgcn_global_load_lds((gbl_void*)g, (lds_void*)l, 16, 0, 0);
}

__device__ __forceinline__ bf16x8 cvt8f(const float* __restrict__ p) {
    float4 f0 = *(const float4*)p;
    float4 f1 = *(const float4*)(p + 4);
    bf16x8 v;
    v[0] = (__bf16)f0.x; v[1] = (__bf16)f0.y; v[2] = (__bf16)f0.z; v[3] = (__bf16)f0.w;
    v[4] = (__bf16)f1.x; v[5] = (__bf16)f1.y; v[6] = (__bf16)f1.z; v[7] = (__bf16)f1.w;
    return v;
}

// ---------------------------------------------------------------------------
// Weight fp32 -> bf16 converter (small, stays a separate kernel)
// ---------------------------------------------------------------------------
__global__ __launch_bounds__(256)
void convert_w(const float* __restrict__ wq, const float* __restrict__ wk,
               const float* __restrict__ wv, const float* __restrict__ wo,
               __bf16* __restrict__ out)
{
    const int z = blockIdx.y;
    const float* src = (z == 0) ? wq : (z == 1) ? wk : (z == 2) ? wv : wo;
    __bf16* dst = out + (size_t)z * DIM * DIM;
    const int i = (blockIdx.x * 256 + threadIdx.x) * 8;
    *(bf16x8*)(dst + i) = cvt8f(src + i);
}

// ---------------------------------------------------------------------------
// Batched QKV projection GEMM: z in {0,1,2} selects (query,Wq)->Qp,
// (keys,Wk)->Kp, (values,Wv)->Vt(transposed). A is fp32, converted to bf16
// during reg-staged A-staging.
// ---------------------------------------------------------------------------
__global__ __launch_bounds__(256, 3)
void gemm_qkv(const float* __restrict__ Aq, const float* __restrict__ Ak,
              const float* __restrict__ Av, const __bf16* __restrict__ Wb,
              __bf16* __restrict__ Qp, __bf16* __restrict__ Kp,
              __bf16* __restrict__ Vtp)
{
    const int z = blockIdx.z;
    const float* Ap = (z == 0) ? Aq : (z == 1) ? Ak : Av;
    const __bf16* Bp = Wb + (size_t)z * DIM * DIM;
    __bf16* Cp = (z == 0) ? Qp : (z == 1) ? Kp : Vtp;

    __shared__ __align__(16) char smem[128 * 132 * 2];   // 33792 B
    __bf16* As = (__bf16*)smem;                // [128][64]
    __bf16* Bs = (__bf16*)(smem + 16384);      // [128][64]

    const int tid  = threadIdx.x;
    const int wave = tid >> 6;
    const int lane = tid & 63;
    const int quad = lane >> 4;
    const int l16  = lane & 15;
    const int m0 = blockIdx.x * 128;
    const int n0 = blockIdx.y * 128;
    const int wm = (wave >> 1) * 64;
    const int wn = (wave & 1) * 64;

    f32x4 acc[4][4] = {};

    for (int k0 = 0; k0 < DIM; k0 += 64) {
        #pragma unroll
        for (int i = 0; i < 4; i++) {
            const int j = wave * 4 + i;
            const int t = j * 64 + lane;
            const int row = t >> 3, c8 = t & 7;
            glds16(Bp + (size_t)(n0 + row) * DIM + k0 + c8 * 8, &Bs[j * 512]);
            *(bf16x8*)&As[t * 8] =
                cvt8f(Ap + (size_t)(m0 + row) * DIM + k0 + c8 * 8);
        }
        __syncthreads();
        #pragma unroll
        for (int kk = 0; kk < 2; kk++) {
            bf16x8 af[4], bg[4];
            #pragma unroll
            for (int mt = 0; mt < 4; mt++)
                af[mt] = *(const bf16x8*)&As[(wm + mt * 16 + l16) * 64 + kk * 32 + quad * 8];
            #pragma unroll
            for (int nt = 0; nt < 4; nt++)
                bg[nt] = *(const bf16x8*)&Bs[(wn + nt * 16 + l16) * 64 + kk * 32 + quad * 8];
            #pragma unroll
            for (int mt = 0; mt < 4; mt++)
                #pragma unroll
                for (int nt = 0; nt < 4; nt++)
                    acc[mt][nt] = MFMA16(af[mt], bg[nt], acc[mt][nt]);
        }
        __syncthreads();
    }

    if (z < 2) {
        #pragma unroll
        for (int mt = 0; mt < 4; mt++)
            #pragma unroll
            for (int nt = 0; nt < 4; nt++)
                #pragma unroll
                for (int r = 0; r < 4; r++)
                    Cp[(size_t)(m0 + wm + mt * 16 + quad * 4 + r) * DIM
                       + n0 + wn + nt * 16 + l16] = (__bf16)acc[mt][nt][r];
    } else {
        // transpose epilogue: Vt[nb][d][s]
        __bf16* Tt = (__bf16*)smem;            // [128][132]
        __syncthreads();
        #pragma unroll
        for (int mt = 0; mt < 4; mt++)
            #pragma unroll
            for (int nt = 0; nt < 4; nt++)
                #pragma unroll
                for (int r = 0; r < 4; r++)
                    Tt[(wm + mt * 16 + quad * 4 + r) * 132 + wn + nt * 16 + l16]
                        = (__bf16)acc[mt][nt][r];
        __syncthreads();
        const int nb  = m0 >> 12;
        const int s0m = m0 & 4095;
        const int d   = tid >> 1;
        const int sh  = (tid & 1) * 64;
        __bf16* dst = Cp + (size_t)nb * DIM * SEQ + (size_t)(n0 + d) * SEQ + s0m + sh;
        #pragma unroll
        for (int i = 0; i < 8; i++) {
            bf16x8 vv;
            #pragma unroll
            for (int e = 0; e < 8; e++) vv[e] = Tt[(sh + i * 8 + e) * 132 + d];
            *(bf16x8*)(dst + i * 8) = vv;
        }
    }
}

// ---------------------------------------------------------------------------
// Output GEMM: C(fp32) = A(bf16) @ Wo(bf16)^T + bias (m97 structure)
// ---------------------------------------------------------------------------
__global__ __launch_bounds__(256, 3)
void gemm_out(const __bf16* __restrict__ Ap, const __bf16* __restrict__ Bp,
              float* __restrict__ Cp, const float* __restrict__ bias)
{
    __shared__ __align__(16) __bf16 As[128 * 64];
    __shared__ __align__(16) __bf16 Bs[128 * 64];
    const int tid  = threadIdx.x;
    const int wave = tid >> 6;
    const int lane = tid & 63;
    const int quad = lane >> 4;
    const int l16  = lane & 15;
    const int m0 = blockIdx.x * 128;
    const int n0 = blockIdx.y * 128;
    const int wm = (wave >> 1) * 64;
    const int wn = (wave & 1) * 64;

    f32x4 acc[4][4] = {};

    for (int k0 = 0; k0 < DIM; k0 += 64) {
        #pragma unroll
        for (int i = 0; i < 4; i++) {
            const int j = wave * 4 + i;
            const int c = j * 64 + lane;
            const int row = c >> 3, c8 = c & 7;
            glds16(Ap + (size_t)(m0 + row) * DIM + k0 + c8 * 8, &As[j * 512]);
            glds16(Bp + (size_t)(n0 + row) * DIM + k0 + c8 * 8, &Bs[j * 512]);
        }
        __syncthreads();
        #pragma unroll
        for (int kk = 0; kk < 2; kk++) {
            bf16x8 af[4], bg[4];
            #pragma unroll
            for (int mt = 0; mt < 4; mt++)
                af[mt] = *(const bf16x8*)&As[(wm + mt * 16 + l16) * 64 + kk * 32 + quad * 8];
            #pragma unroll
            for (int nt = 0; nt < 4; nt++)
                bg[nt] = *(const bf16x8*)&Bs[(wn + nt * 16 + l16) * 64 + kk * 32 + quad * 8];
            #pragma unroll
            for (int mt = 0; mt < 4; mt++)
                #pragma unroll
                for (int nt = 0; nt < 4; nt++)
                    acc[mt][nt] = MFMA16(af[mt], bg[nt], acc[mt][nt]);
        }
        __syncthreads();
    }
    #pragma unroll
    for (int mt = 0; mt < 4; mt++)
        #pragma unroll
        for (int nt = 0; nt < 4; nt++)
            #pragma unroll
            for (int r = 0; r < 4; r++) {
                const int col = n0 + wn + nt * 16 + l16;
                Cp[(size_t)(m0 + wm + mt * 16 + quad * 4 + r) * DIM + col]
                    = acc[mt][nt][r] + bias[col];
            }
}

// ---------------------------------------------------------------------------
// Flash attention v10 — Q in registers. The MFMA32 B-fragment is lane-local
// in Q (lane (l32,half) needs Q[q][dc*64+ks*16+half*8 ..+7] only), so Q is
// prefetched per-chunk from global (L2-hot) into double-buffered named reg
// arrays instead of staged through LDS. Deletes: all Q LDS B-reads (2/3 of
// K-phase LDS traffic), Q staging DMA, Q dbuf region (LDS 119->102 KB), and
// the Q-read bank conflicts. Everything else identical to proven v8.
// ---------------------------------------------------------------------------
#define MKC(v, r4) ((r4) == 0 ? (v).x : (r4) == 1 ? (v).y : (r4) == 2 ? (v).z : (v).w)

__global__ __launch_bounds__(512, 1)
void flash_attn(__bf16* __restrict__ Qp, const __bf16* __restrict__ Kp,
                const __bf16* __restrict__ Vt, const int* __restrict__ mask)
{
    constexpr float SCALE = 0.044194173824159216f;   // 1/sqrt(512)

    __shared__ __bf16 KV[2][16384];     // 2x32KB: K [256 kc][64 d] / V [256 d][64 kc]
    __shared__ __bf16 P[64 * 256];      // 32 KB, swizzled
    __shared__ float pmax[8 * 66];
    __shared__ float psum[8 * 66];

    const int bid  = blockIdx.x;
    const int n    = bid & 3;            // batch -> XCD-local K/V
    const int q0   = (bid >> 2) * 64;
    const int tid  = threadIdx.x;
    const int w    = tid >> 6;
    const int lane = tid & 63;
    const int l32  = lane & 31;
    const int half = lane >> 5;
    const int r8   = lane >> 3;          // 0..7
    const int c8   = lane & 7;
    const int gc   = c8 ^ r8;            // swizzle-compensated global chunk

    const __bf16* Qb = Qp + (size_t)n * SEQ * DIM;
    const __bf16* Kb = Kp + (size_t)n * SEQ * DIM;
    const __bf16* Vb = Vt + (size_t)n * DIM * SEQ;
    const int*    Mb = mask + (size_t)n * SEQ * SEQ;
    __bf16*       AO = Qp + (size_t)n * SEQ * DIM;   // alias; rows consumed first

    auto stageK = [&](int slot, int k0, int dc) {
        #pragma unroll
        for (int i = 0; i < 4; i++) {
            const int R = (i * 8 + w) * 8 + r8;
            glds16(Kb + (size_t)(k0 + R) * DIM + dc * 64 + gc * 8,
                   &KV[slot][(i * 8 + w) * 512]);
        }
    };
    auto stageV = [&](int slot, int k0, int vc) {    // vc = h*4 + kc2
        const int h = vc >> 2, kc2 = vc & 3;
        #pragma unroll
        for (int i = 0; i < 4; i++) {
            const int R = (i * 8 + w) * 8 + r8;      // local d-row
            glds16(Vb + (size_t)(h * 256 + R) * SEQ + k0 + kc2 * 64 + gc * 8,
                   &KV[slot][(i * 8 + w) * 512]);
        }
    };

    // Q fragment base pointers for this lane's two q-rows (B-frag is
    // lane-local: d = dc*64 + ks*16 + half*8 + e)
    const __bf16* qr0 = Qb + (size_t)(q0 + l32) * DIM + half * 8;
    const __bf16* qr1 = qr0 + (size_t)32 * DIM;
    bf16x8 qcA[4], qcB[4], qnA[4], qnB[4];
    auto loadQ = [&](bf16x8* qa, bf16x8* qb, int dc) {
        #pragma unroll
        for (int ks = 0; ks < 4; ks++) {
            qa[ks] = *(const bf16x8*)(qr0 + dc * 64 + ks * 16);
            qb[ks] = *(const bf16x8*)(qr1 + dc * 64 + ks * 16);
        }
    };

    float m0 = -__builtin_inff(), m1 = -__builtin_inff();
    float l0 = 0.f, l1 = 0.f;
    f32x16 o00 = {}, o01 = {}, o10 = {}, o11 = {};   // [h][qh]

    // ---- prologue: stage first K chunk into slot 0; load Q frags for dc=0
    stageK(0, 0, 0);
    loadQ(qcA, qcB, 0);
    __syncthreads();
    int cur = 0;

    #pragma unroll 1
    for (int j = 0; j < 16; j++) {
        const int k0 = j * 256;

        // ---- mask in C-fragment layout: lane (w,l32,half) covers
        // kc = 32w + 8g + 4*half + r4 for q = l32 and q = 32+l32
        int4 mk0[4], mk1[4];
        {
            const int* mp0 = Mb + (size_t)(q0 + l32) * SEQ + k0 + 32 * w + 4 * half;
            const int* mp1 = mp0 + (size_t)32 * SEQ;
            #pragma unroll
            for (int g = 0; g < 4; g++) {
                mk0[g] = *(const int4*)(mp0 + 8 * g);
                mk1[g] = *(const int4*)(mp1 + 8 * g);
            }
        }

        // ---- phase 1: S^T scores, dbuf'd K chunks [256 kc][64 d], Q in regs
        f32x16 s0 = {}, s1 = {};
        #pragma unroll 1
        for (int dc = 0; dc < 8; dc++) {
            const int nxt = cur ^ 1;
            if (dc < 7) stageK(nxt, k0, dc + 1);
            else        stageV(nxt, k0, 0);
            loadQ(qnA, qnB, (dc + 1) & 7);           // prefetch next chunk's Q
            const __bf16* Kc = KV[cur];
            __builtin_amdgcn_s_setprio(1);
            #pragma unroll
            for (int ks = 0; ks < 4; ks++) {
                const int ch = (2 * ks + half) ^ (l32 & 7);      // row&7 == l32&7
                bf16x8 a = *(const bf16x8*)&Kc[(32 * w + l32) * 64 + ch * 8];
                s0 = MFMA32(a, qcA[ks], s0);
                s1 = MFMA32(a, qcB[ks], s1);
            }
            __builtin_amdgcn_s_setprio(0);
            if (dc == 7) {
                // per-lane partial max + pmax store
                float mx0 = s0[0], mx1 = s1[0];
                #pragma unroll
                for (int r = 1; r < 16; r++) { mx0 = fmaxf(mx0, s0[r]); mx1 = fmaxf(mx1, s1[r]); }
                mx0 = fmaxf(mx0, __shfl_xor(mx0, 32));
                mx1 = fmaxf(mx1, __shfl_xor(mx1, 32));
                if (half == 0) pmax[w * 66 + l32]      = mx0;
                else           pmax[w * 66 + 32 + l32] = mx1;
            }
            __syncthreads();
            cur = nxt;
            #pragma unroll
            for (int ks = 0; ks < 4; ks++) { qcA[ks] = qnA[ks]; qcB[ks] = qnB[ks]; }
        }

        // ---- combine max; per-lane softmax state for q=l32 (0) / q=32+l32 (1)
        float mp0v = pmax[l32], mp1v = pmax[32 + l32];
        #pragma unroll
        for (int w2 = 1; w2 < 8; w2++) {
            mp0v = fmaxf(mp0v, pmax[w2 * 66 + l32]);
            mp1v = fmaxf(mp1v, pmax[w2 * 66 + 32 + l32]);
        }
        const float mn0 = fmaxf(m0, mp0v * SCALE);
        const float mn1 = fmaxf(m1, mp1v * SCALE);
        const float a0 = __expf(m0 - mn0);
        const float a1 = __expf(m1 - mn1);
        m0 = mn0; m1 = mn1;
        #pragma unroll
        for (int r = 0; r < 16; r++) {
            o00[r] *= a0; o10[r] *= a0;
            o01[r] *= a1; o11[r] *= a1;
        }

        // ---- exp + register-mask + vectorized P write + partial lsum
        float ls0 = 0.f, ls1 = 0.f;
        #pragma unroll
        for (int g = 0; g < 4; g++) {
            bf16x4 pv0, pv1;
            #pragma unroll
            for (int r4 = 0; r4 < 4; r4++) {
                const int r = g * 4 + r4;
                float p0 = __expf(s0[r] * SCALE - mn0);
                float p1 = __expf(s1[r] * SCALE - mn1);
                p0 = MKC(mk0[g], r4) ? p0 : 0.f;
                p1 = MKC(mk1[g], r4) ? p1 : 0.f;
                ls0 += p0; ls1 += p1;
                pv0[r4] = (__bf16)p0;
                pv1[r4] = (__bf16)p1;
            }
            const int c  = 4 * w + g;                        // kcol chunk 0..31
            const int cp = (c & 24) | ((c & 7) ^ (l32 & 7));
            *(bf16x4*)&P[l32 * 256 + cp * 8 + 4 * half]        = pv0;
            *(bf16x4*)&P[(32 + l32) * 256 + cp * 8 + 4 * half] = pv1;
        }
        ls0 += __shfl_xor(ls0, 32);
        ls1 += __shfl_xor(ls1, 32);
        if (half == 0) psum[w * 66 + l32]      = ls0;
        else           psum[w * 66 + 32 + l32] = ls1;
        __syncthreads();   // B (P + psum ready; V chunk 0 staged long ago)

        {
            float ss0 = 0.f, ss1 = 0.f;
            #pragma unroll
            for (int w2 = 0; w2 < 8; w2++) {
                ss0 += psum[w2 * 66 + l32];
                ss1 += psum[w2 * 66 + 32 + l32];
            }
            l0 = l0 * a0 + ss0;
            l1 = l1 * a1 + ss1;
        }

        // ---- phase 3: PV, dbuf'd V chunks [256 d][64 kc]; prefetch next K
        #pragma unroll 1
        for (int vc = 0; vc < 8; vc++) {
            const int nxt = cur ^ 1;
            if (vc < 7)      stageV(nxt, k0, vc + 1);
            else if (j < 15) stageK(nxt, k0 + 256, 0);
            const __bf16* Vc = KV[cur];
            const int kc2 = vc & 3;
            __builtin_amdgcn_s_setprio(1);
            #pragma unroll
            for (int ks = 0; ks < 4; ks++) {
                const int ca = (2 * ks + half) ^ (l32 & 7);  // row&7 == l32&7
                bf16x8 a = *(const bf16x8*)&Vc[(32 * w + l32) * 64 + ca * 8];
                const int ck = kc2 * 8 + 2 * ks + half;      // P kcol chunk
                const int cp = (ck & 24) | ((ck & 7) ^ (l32 & 7));
                bf16x8 b0 = *(const bf16x8*)&P[l32 * 256 + cp * 8];
                bf16x8 b1 = *(const bf16x8*)&P[(32 + l32) * 256 + cp * 8];
                if (vc < 4) { o00 = MFMA32(a, b0, o00); o01 = MFMA32(a, b1, o01); }
                else        { o10 = MFMA32(a, b0, o10); o11 = MFMA32(a, b1, o11); }
            }
            __builtin_amdgcn_s_setprio(0);
            __syncthreads();
            cur = nxt;
        }
    }

    // ---- epilogue: AO[q][d] = O^T[d][q] / l
    const float li0 = 1.f / l0, li1 = 1.f / l1;
    __bf16* ao0 = AO + (size_t)(q0 + l32) * DIM;
    __bf16* ao1 = AO + (size_t)(q0 + 32 + l32) * DIM;
    #pragma unroll
    for (int h = 0; h < 2; h++) {
        #pragma unroll
        for (int g = 0; g < 4; g++) {
            bf16x4 v00, v01;
            #pragma unroll
            for (int r4 = 0; r4 < 4; r4++) {
                const int r = g * 4 + r4;
                v00[r4] = (__bf16)((h ? o10[r] : o00[r]) * li0);
                v01[r4] = (__bf16)((h ? o11[r] : o01[r]) * li1);
            }
            const int d = h * 256 + 32 * w + g * 8 + 4 * half;
            *(bf16x4*)&ao0[d] = v00;
            *(bf16x4*)&ao1[d] = v01;
        }
    }
}

// ---------------------------------------------------------------------------
extern "C" void kernel_launch(void* const* d_in, const int* in_sizes, int n_in,
                              void* d_out, int out_size, void* d_ws, size_t ws_size,
                              hipStream_t stream)
{
    const float* values = (const float*)d_in[0];
    const float* keys   = (const float*)d_in[1];
    const float* query  = (const float*)d_in[2];
    const int*   mask   = (const int*)d_in[3];
    const float* Wv = (const float*)d_in[4];
    const float* Wk = (const float*)d_in[5];
    const float* Wq = (const float*)d_in[6];
    const float* Wo = (const float*)d_in[7];
    const float* bo = (const float*)d_in[8];
    float* out = (float*)d_out;

    char* ws = (char*)d_ws;
    __bf16* Qp  = (__bf16*)(ws);                 // 16 MiB (AO aliases)
    __bf16* Kp  = (__bf16*)(ws + (16u << 20));   // 16 MiB
    __bf16* Vt  = (__bf16*)(ws + (32u << 20));   // 16 MiB
    __bf16* wbf = (__bf16*)(ws + (48u << 20));   // 2 MiB

    const int M = 4 * SEQ;  // 16384

    convert_w<<<dim3(128, 4), 256, 0, stream>>>(Wq, Wk, Wv, Wo, wbf);

    // batched Q/K/V projection with fused fp32->bf16 A conversion
    gemm_qkv<<<dim3(M / 128, DIM / 128, 3), 256, 0, stream>>>(
        query, keys, values, wbf, Qp, Kp, Vt);

    flash_attn<<<256, 512, 0, stream>>>(Qp, Kp, Vt, mask);

    gemm_out<<<dim3(M / 128, DIM / 128), 256, 0, stream>>>(
        Qp /*AO*/, wbf + 3 * DIM * DIM, out, bo);
}

// Round 5
// 811.148 us; speedup vs baseline: 1.2647x; 1.2647x over previous
//
#include <hip/hip_runtime.h>

typedef __bf16 bf16x8 __attribute__((ext_vector_type(8)));
typedef __bf16 bf16x4 __attribute__((ext_vector_type(4)));
typedef float f32x4 __attribute__((ext_vector_type(4)));
typedef float f32x16 __attribute__((ext_vector_type(16)));

#define MFMA16(a, b, c) __builtin_amdgcn_mfma_f32_16x16x32_bf16((a), (b), (c), 0, 0, 0)
#define MFMA32(a, b, c) __builtin_amdgcn_mfma_f32_32x32x16_bf16((a), (b), (c), 0, 0, 0)

static constexpr int SEQ = 4096;
static constexpr int DIM = 512;

typedef __attribute__((address_space(3))) void lds_void;
typedef __attribute__((address_space(1))) const void gbl_void;

__device__ __forceinline__ void glds16(const void* g, void* l) {
    __builtin_amdgcn_global_load_lds((gbl_void*)g, (lds_void*)l, 16, 0, 0);
}

__device__ __forceinline__ bf16x8 cvt8f(const float* __restrict__ p) {
    float4 f0 = *(const float4*)p;
    float4 f1 = *(const float4*)(p + 4);
    bf16x8 v;
    v[0] = (__bf16)f0.x; v[1] = (__bf16)f0.y; v[2] = (__bf16)f0.z; v[3] = (__bf16)f0.w;
    v[4] = (__bf16)f1.x; v[5] = (__bf16)f1.y; v[6] = (__bf16)f1.z; v[7] = (__bf16)f1.w;
    return v;
}

// ---------------------------------------------------------------------------
// Weight fp32 -> bf16 converter
// ---------------------------------------------------------------------------
__global__ __launch_bounds__(256)
void convert_w(const float* __restrict__ wq, const float* __restrict__ wk,
               const float* __restrict__ wv, const float* __restrict__ wo,
               __bf16* __restrict__ out)
{
    const int z = blockIdx.y;
    const float* src = (z == 0) ? wq : (z == 1) ? wk : (z == 2) ? wv : wo;
    __bf16* dst = out + (size_t)z * DIM * DIM;
    const int i = (blockIdx.x * 256 + threadIdx.x) * 8;
    *(bf16x8*)(dst + i) = cvt8f(src + i);
}

// ---------------------------------------------------------------------------
// Batched QKV projection GEMM (proven R3): z in {0,1,2} -> Qp, Kp, Vt^T.
// A fp32 converted during reg-staged A-staging.
// ---------------------------------------------------------------------------
__global__ __launch_bounds__(256, 3)
void gemm_qkv(const float* __restrict__ Aq, const float* __restrict__ Ak,
              const float* __restrict__ Av, const __bf16* __restrict__ Wb,
              __bf16* __restrict__ Qp, __bf16* __restrict__ Kp,
              __bf16* __restrict__ Vtp)
{
    const int z = blockIdx.z;
    const float* Ap = (z == 0) ? Aq : (z == 1) ? Ak : Av;
    const __bf16* Bp = Wb + (size_t)z * DIM * DIM;
    __bf16* Cp = (z == 0) ? Qp : (z == 1) ? Kp : Vtp;

    __shared__ __align__(16) char smem[128 * 132 * 2];   // 33792 B
    __bf16* As = (__bf16*)smem;                // [128][64]
    __bf16* Bs = (__bf16*)(smem + 16384);      // [128][64]

    const int tid  = threadIdx.x;
    const int wave = tid >> 6;
    const int lane = tid & 63;
    const int quad = lane >> 4;
    const int l16  = lane & 15;
    const int m0 = blockIdx.x * 128;
    const int n0 = blockIdx.y * 128;
    const int wm = (wave >> 1) * 64;
    const int wn = (wave & 1) * 64;

    f32x4 acc[4][4] = {};

    for (int k0 = 0; k0 < DIM; k0 += 64) {
        #pragma unroll
        for (int i = 0; i < 4; i++) {
            const int j = wave * 4 + i;
            const int t = j * 64 + lane;
            const int row = t >> 3, c8 = t & 7;
            glds16(Bp + (size_t)(n0 + row) * DIM + k0 + c8 * 8, &Bs[j * 512]);
            *(bf16x8*)&As[t * 8] =
                cvt8f(Ap + (size_t)(m0 + row) * DIM + k0 + c8 * 8);
        }
        __syncthreads();
        #pragma unroll
        for (int kk = 0; kk < 2; kk++) {
            bf16x8 af[4], bg[4];
            #pragma unroll
            for (int mt = 0; mt < 4; mt++)
                af[mt] = *(const bf16x8*)&As[(wm + mt * 16 + l16) * 64 + kk * 32 + quad * 8];
            #pragma unroll
            for (int nt = 0; nt < 4; nt++)
                bg[nt] = *(const bf16x8*)&Bs[(wn + nt * 16 + l16) * 64 + kk * 32 + quad * 8];
            #pragma unroll
            for (int mt = 0; mt < 4; mt++)
                #pragma unroll
                for (int nt = 0; nt < 4; nt++)
                    acc[mt][nt] = MFMA16(af[mt], bg[nt], acc[mt][nt]);
        }
        __syncthreads();
    }

    if (z < 2) {
        #pragma unroll
        for (int mt = 0; mt < 4; mt++)
            #pragma unroll
            for (int nt = 0; nt < 4; nt++)
                #pragma unroll
                for (int r = 0; r < 4; r++)
                    Cp[(size_t)(m0 + wm + mt * 16 + quad * 4 + r) * DIM
                       + n0 + wn + nt * 16 + l16] = (__bf16)acc[mt][nt][r];
    } else {
        // transpose epilogue: Vt[nb][d][s]
        __bf16* Tt = (__bf16*)smem;            // [128][132]
        __syncthreads();
        #pragma unroll
        for (int mt = 0; mt < 4; mt++)
            #pragma unroll
            for (int nt = 0; nt < 4; nt++)
                #pragma unroll
                for (int r = 0; r < 4; r++)
                    Tt[(wm + mt * 16 + quad * 4 + r) * 132 + wn + nt * 16 + l16]
                        = (__bf16)acc[mt][nt][r];
        __syncthreads();
        const int nb  = m0 >> 12;
        const int s0m = m0 & 4095;
        const int d   = tid >> 1;
        const int sh  = (tid & 1) * 64;
        __bf16* dst = Cp + (size_t)nb * DIM * SEQ + (size_t)(n0 + d) * SEQ + s0m + sh;
        #pragma unroll
        for (int i = 0; i < 8; i++) {
            bf16x8 vv;
            #pragma unroll
            for (int e = 0; e < 8; e++) vv[e] = Tt[(sh + i * 8 + e) * 132 + d];
            *(bf16x8*)(dst + i * 8) = vv;
        }
    }
}

// ---------------------------------------------------------------------------
// Output GEMM: C(fp32) = A(bf16) @ Wo(bf16)^T + bias (m97 structure)
// ---------------------------------------------------------------------------
__global__ __launch_bounds__(256, 3)
void gemm_out(const __bf16* __restrict__ Ap, const __bf16* __restrict__ Bp,
              float* __restrict__ Cp, const float* __restrict__ bias)
{
    __shared__ __align__(16) __bf16 As[128 * 64];
    __shared__ __align__(16) __bf16 Bs[128 * 64];
    const int tid  = threadIdx.x;
    const int wave = tid >> 6;
    const int lane = tid & 63;
    const int quad = lane >> 4;
    const int l16  = lane & 15;
    const int m0 = blockIdx.x * 128;
    const int n0 = blockIdx.y * 128;
    const int wm = (wave >> 1) * 64;
    const int wn = (wave & 1) * 64;

    f32x4 acc[4][4] = {};

    for (int k0 = 0; k0 < DIM; k0 += 64) {
        #pragma unroll
        for (int i = 0; i < 4; i++) {
            const int j = wave * 4 + i;
            const int c = j * 64 + lane;
            const int row = c >> 3, c8 = c & 7;
            glds16(Ap + (size_t)(m0 + row) * DIM + k0 + c8 * 8, &As[j * 512]);
            glds16(Bp + (size_t)(n0 + row) * DIM + k0 + c8 * 8, &Bs[j * 512]);
        }
        __syncthreads();
        #pragma unroll
        for (int kk = 0; kk < 2; kk++) {
            bf16x8 af[4], bg[4];
            #pragma unroll
            for (int mt = 0; mt < 4; mt++)
                af[mt] = *(const bf16x8*)&As[(wm + mt * 16 + l16) * 64 + kk * 32 + quad * 8];
            #pragma unroll
            for (int nt = 0; nt < 4; nt++)
                bg[nt] = *(const bf16x8*)&Bs[(wn + nt * 16 + l16) * 64 + kk * 32 + quad * 8];
            #pragma unroll
            for (int mt = 0; mt < 4; mt++)
                #pragma unroll
                for (int nt = 0; nt < 4; nt++)
                    acc[mt][nt] = MFMA16(af[mt], bg[nt], acc[mt][nt]);
        }
        __syncthreads();
    }
    #pragma unroll
    for (int mt = 0; mt < 4; mt++)
        #pragma unroll
        for (int nt = 0; nt < 4; nt++)
            #pragma unroll
            for (int r = 0; r < 4; r++) {
                const int col = n0 + wn + nt * 16 + l16;
                Cp[(size_t)(m0 + wm + mt * 16 + quad * 4 + r) * DIM + col]
                    = acc[mt][nt][r] + bias[col];
            }
}

// ---------------------------------------------------------------------------
// Flash attention v11 — R2's triple-buffered counted-vmcnt protocol (its
// correctness passed on HW), with ONE change: BARRIER() is a raw s_barrier
// with compiler memory clobber, NO sched_barrier(0). A/B isolates the
// order-pinning as R2's regression cause (m141 prior: order-pinning alone
// cost 42%). Per chunk t: wait vmcnt(keep t+1); barrier; stage(t+2);
// compute(t). vmcnt never drains to 0 in the main loop (T4).
// ---------------------------------------------------------------------------
#define MKC(v, r4) ((r4) == 0 ? (v).x : (r4) == 1 ? (v).y : (r4) == 2 ? (v).z : (v).w)
#define WAITVM(n)  asm volatile("s_waitcnt vmcnt(" #n ")" ::: "memory")
#define WAITLGKM() asm volatile("s_waitcnt lgkmcnt(0)" ::: "memory")
#define BARRIER()  asm volatile("s_barrier" ::: "memory")

__global__ __launch_bounds__(512, 1)
void flash_attn(__bf16* __restrict__ Qp, const __bf16* __restrict__ Kp,
                const __bf16* __restrict__ Vt, const int* __restrict__ mask)
{
    constexpr float SCALE = 0.044194173824159216f;   // 1/sqrt(512)

    __shared__ __bf16 KQ[3 * 20480];    // 3 slots x 40KB: K/V [256][64] @0, Q [64][64] @16384
    __shared__ __bf16 P[64 * 256];      // 32 KB, swizzled
    __shared__ float pmax[8 * 66];
    __shared__ float psum[8 * 66];

    const int bid  = blockIdx.x;
    const int n    = bid & 3;            // batch -> XCD-local K/V
    const int q0   = (bid >> 2) * 64;
    const int tid  = threadIdx.x;
    const int w    = tid >> 6;
    const int lane = tid & 63;
    const int l32  = lane & 31;
    const int half = lane >> 5;
    const int r8   = lane >> 3;          // 0..7
    const int c8   = lane & 7;
    const int gc   = c8 ^ r8;            // swizzle-compensated global chunk

    const __bf16* Qb = Qp + (size_t)n * SEQ * DIM;
    const __bf16* Kb = Kp + (size_t)n * SEQ * DIM;
    const __bf16* Vb = Vt + (size_t)n * DIM * SEQ;
    const int*    Mb = mask + (size_t)n * SEQ * SEQ;
    __bf16*       AO = Qp + (size_t)n * SEQ * DIM;   // alias; rows consumed first

    auto stageK = [&](int slot, int k0, int dc) {
        __bf16* dst = &KQ[slot * 20480];
        #pragma unroll
        for (int i = 0; i < 4; i++) {
            const int R = (i * 8 + w) * 8 + r8;
            glds16(Kb + (size_t)(k0 + R) * DIM + dc * 64 + gc * 8,
                   &dst[(i * 8 + w) * 512]);
        }
    };
    auto stageV = [&](int slot, int k0, int vc) {    // vc = h*4 + kc2
        __bf16* dst = &KQ[slot * 20480];
        const int h = vc >> 2, kc2 = vc & 3;
        #pragma unroll
        for (int i = 0; i < 4; i++) {
            const int R = (i * 8 + w) * 8 + r8;      // local d-row
            glds16(Vb + (size_t)(h * 256 + R) * SEQ + k0 + kc2 * 64 + gc * 8,
                   &dst[(i * 8 + w) * 512]);
        }
    };
    auto stageQ = [&](int slot, int dc) {            // [64 q][64 d], 1 glds16/thr
        glds16(Qb + (size_t)(q0 + w * 8 + r8) * DIM + dc * 64 + gc * 8,
               &KQ[slot * 20480 + 16384 + w * 512]);
    };

    float m0 = -__builtin_inff(), m1 = -__builtin_inff();
    float l0 = 0.f, l1 = 0.f;
    f32x16 o00 = {}, o01 = {}, o10 = {}, o11 = {};   // [h][qh]

    // ---- prologue: stage chunks 0,1 (K0,K1 of j=0) into slots 0,1
    stageK(0, 0, 0); stageQ(0, 0);
    stageK(1, 0, 1); stageQ(1, 1);
    int cur = 0;

    #pragma unroll 1
    for (int j = 0; j < 16; j++) {
        const int k0 = j * 256;

        // ---- mask in C-fragment layout: lane (w,l32,half) covers
        // kc = 32w + 8g + 4*half + r4 for q = l32 and q = 32+l32
        int4 mk0[4], mk1[4];
        {
            const int* mp0 = Mb + (size_t)(q0 + l32) * SEQ + k0 + 32 * w + 4 * half;
            const int* mp1 = mp0 + (size_t)32 * SEQ;
            #pragma unroll
            for (int g = 0; g < 4; g++) {
                mk0[g] = *(const int4*)(mp0 + 8 * g);
                mk1[g] = *(const int4*)(mp1 + 8 * g);
            }
        }

        // ---- phase 1: S^T scores, 8 K-chunks [256 kc][64 d] + Q slice
        f32x16 s0 = {}, s1 = {};
        #pragma unroll 1
        for (int dc = 0; dc < 8; dc++) {
            // entry of chunk t=dc: drain chunk-t loads, keep (t+1)'s in flight
            if (dc < 2)      WAITVM(13);   // K(next)=5 + mask(8) still in FIFO
            else if (dc < 7) WAITVM(5);    // next = K-chunk (5)
            else             WAITVM(4);    // next = V0 (4)
            BARRIER();
            const int s2 = (cur >= 1) ? cur - 1 : cur + 2;   // (cur+2)%3
            if (dc < 6)      { stageK(s2, k0, dc + 2); stageQ(s2, dc + 2); }
            else if (dc == 6)  stageV(s2, k0, 0);
            else               stageV(s2, k0, 1);

            const __bf16* Kc = &KQ[cur * 20480];
            const __bf16* Qc = Kc + 16384;
            __builtin_amdgcn_s_setprio(1);
            #pragma unroll
            for (int ks = 0; ks < 4; ks++) {
                const int ch = (2 * ks + half) ^ (l32 & 7);      // row&7 == l32&7
                bf16x8 a  = *(const bf16x8*)&Kc[(32 * w + l32) * 64 + ch * 8];
                bf16x8 b0 = *(const bf16x8*)&Qc[l32 * 64 + ch * 8];
                bf16x8 b1 = *(const bf16x8*)&Qc[(32 + l32) * 64 + ch * 8];
                s0 = MFMA32(a, b0, s0);
                s1 = MFMA32(a, b1, s1);
            }
            __builtin_amdgcn_s_setprio(0);
            if (dc == 7) {
                // per-lane partial max over this wave's 32 kcols (raw scores)
                float mx0 = s0[0], mx1 = s1[0];
                #pragma unroll
                for (int r = 1; r < 16; r++) { mx0 = fmaxf(mx0, s0[r]); mx1 = fmaxf(mx1, s1[r]); }
                mx0 = fmaxf(mx0, __shfl_xor(mx0, 32));
                mx1 = fmaxf(mx1, __shfl_xor(mx1, 32));
                if (half == 0) pmax[w * 66 + l32]      = mx0;
                else           pmax[w * 66 + 32 + l32] = mx1;
            }
            cur = (cur < 2) ? cur + 1 : 0;
        }

        // ---- B1: pmax visible (V0,V1 stay in flight through softmax)
        WAITLGKM();
        BARRIER();

        // ---- combine max; per-lane softmax state for q=l32 (0) / q=32+l32 (1)
        float mp0v = pmax[l32], mp1v = pmax[32 + l32];
        #pragma unroll
        for (int w2 = 1; w2 < 8; w2++) {
            mp0v = fmaxf(mp0v, pmax[w2 * 66 + l32]);
            mp1v = fmaxf(mp1v, pmax[w2 * 66 + 32 + l32]);
        }
        const float mn0 = fmaxf(m0, mp0v * SCALE);
        const float mn1 = fmaxf(m1, mp1v * SCALE);
        const float a0 = __expf(m0 - mn0);
        const float a1 = __expf(m1 - mn1);
        m0 = mn0; m1 = mn1;
        #pragma unroll
        for (int r = 0; r < 16; r++) {
            o00[r] *= a0; o10[r] *= a0;
            o01[r] *= a1; o11[r] *= a1;
        }

        // ---- exp + register-mask + vectorized P write + partial lsum
        float ls0 = 0.f, ls1 = 0.f;
        #pragma unroll
        for (int g = 0; g < 4; g++) {
            bf16x4 pv0, pv1;
            #pragma unroll
            for (int r4 = 0; r4 < 4; r4++) {
                const int r = g * 4 + r4;
                float p0 = __expf(s0[r] * SCALE - mn0);
                float p1 = __expf(s1[r] * SCALE - mn1);
                p0 = MKC(mk0[g], r4) ? p0 : 0.f;
                p1 = MKC(mk1[g], r4) ? p1 : 0.f;
                ls0 += p0; ls1 += p1;
                pv0[r4] = (__bf16)p0;
                pv1[r4] = (__bf16)p1;
            }
            const int c  = 4 * w + g;                        // kcol chunk 0..31
            const int cp = (c & 24) | ((c & 7) ^ (l32 & 7));
            *(bf16x4*)&P[l32 * 256 + cp * 8 + 4 * half]        = pv0;
            *(bf16x4*)&P[(32 + l32) * 256 + cp * 8 + 4 * half] = pv1;
        }
        ls0 += __shfl_xor(ls0, 32);
        ls1 += __shfl_xor(ls1, 32);
        if (half == 0) psum[w * 66 + l32]      = ls0;
        else           psum[w * 66 + 32 + l32] = ls1;

        // ---- B2 = entry of chunk 8 (V0): drain V0 loads, keep V1's; P visible
        WAITVM(4);
        WAITLGKM();
        BARRIER();

        // V-chunk compute helper
        auto computeV = [&](int slot, int vc) {
            const __bf16* Vc = &KQ[slot * 20480];
            const int kc2 = vc & 3;
            __builtin_amdgcn_s_setprio(1);
            #pragma unroll
            for (int ks = 0; ks < 4; ks++) {
                const int ca = (2 * ks + half) ^ (l32 & 7);  // row&7 == l32&7
                bf16x8 a = *(const bf16x8*)&Vc[(32 * w + l32) * 64 + ca * 8];
                const int ck = kc2 * 8 + 2 * ks + half;      // P kcol chunk
                const int cp = (ck & 24) | ((ck & 7) ^ (l32 & 7));
                bf16x8 b0 = *(const bf16x8*)&P[l32 * 256 + cp * 8];
                bf16x8 b1 = *(const bf16x8*)&P[(32 + l32) * 256 + cp * 8];
                if (vc < 4) { o00 = MFMA32(a, b0, o00); o01 = MFMA32(a, b1, o01); }
                else        { o10 = MFMA32(a, b0, o10); o11 = MFMA32(a, b1, o11); }
            }
            __builtin_amdgcn_s_setprio(0);
        };

        // ---- chunk 8 (V0): stage V2, combine psum, compute
        {
            const int s2 = (cur >= 1) ? cur - 1 : cur + 2;
            stageV(s2, k0, 2);
            float ss0 = 0.f, ss1 = 0.f;
            #pragma unroll
            for (int w2 = 0; w2 < 8; w2++) {
                ss0 += psum[w2 * 66 + l32];
                ss1 += psum[w2 * 66 + 32 + l32];
            }
            l0 = l0 * a0 + ss0;
            l1 = l1 * a1 + ss1;
            computeV(cur, 0);
            cur = (cur < 2) ? cur + 1 : 0;
        }

        // ---- chunks 9..15 (V1..V7); prefetch next-j K0/K1 at vc=6/7
        #pragma unroll 1
        for (int vc = 1; vc < 8; vc++) {
            if (vc < 7) WAITVM(4);          // next = V-chunk (4)
            else if (j < 15) WAITVM(5);     // next = K0 of next j (5)
            else WAITVM(0);                 // last chunk of kernel
            BARRIER();
            const int s2 = (cur >= 1) ? cur - 1 : cur + 2;
            if (vc < 6)        stageV(s2, k0, vc + 2);
            else if (vc == 6) { if (j < 15) { stageK(s2, k0 + 256, 0); stageQ(s2, 0); } }
            else              { if (j < 15) { stageK(s2, k0 + 256, 1); stageQ(s2, 1); } }
            computeV(cur, vc);
            cur = (cur < 2) ? cur + 1 : 0;
        }
    }

    // ---- epilogue: AO[q][d] = O^T[d][q] / l
    const float li0 = 1.f / l0, li1 = 1.f / l1;
    __bf16* ao0 = AO + (size_t)(q0 + l32) * DIM;
    __bf16* ao1 = AO + (size_t)(q0 + 32 + l32) * DIM;
    #pragma unroll
    for (int h = 0; h < 2; h++) {
        #pragma unroll
        for (int g = 0; g < 4; g++) {
            bf16x4 v00, v01;
            #pragma unroll
            for (int r4 = 0; r4 < 4; r4++) {
                const int r = g * 4 + r4;
                v00[r4] = (__bf16)((h ? o10[r] : o00[r]) * li0);
                v01[r4] = (__bf16)((h ? o11[r] : o01[r]) * li1);
            }
            const int d = h * 256 + 32 * w + g * 8 + 4 * half;
            *(bf16x4*)&ao0[d] = v00;
            *(bf16x4*)&ao1[d] = v01;
        }
    }
}

// ---------------------------------------------------------------------------
extern "C" void kernel_launch(void* const* d_in, const int* in_sizes, int n_in,
                              void* d_out, int out_size, void* d_ws, size_t ws_size,
                              hipStream_t stream)
{
    const float* values = (const float*)d_in[0];
    const float* keys   = (const float*)d_in[1];
    const float* query  = (const float*)d_in[2];
    const int*   mask   = (const int*)d_in[3];
    const float* Wv = (const float*)d_in[4];
    const float* Wk = (const float*)d_in[5];
    const float* Wq = (const float*)d_in[6];
    const float* Wo = (const float*)d_in[7];
    const float* bo = (const float*)d_in[8];
    float* out = (float*)d_out;

    char* ws = (char*)d_ws;
    __bf16* Qp  = (__bf16*)(ws);                 // 16 MiB (AO aliases)
    __bf16* Kp  = (__bf16*)(ws + (16u << 20));   // 16 MiB
    __bf16* Vt  = (__bf16*)(ws + (32u << 20));   // 16 MiB
    __bf16* wbf = (__bf16*)(ws + (48u << 20));   // 2 MiB

    const int M = 4 * SEQ;  // 16384

    convert_w<<<dim3(128, 4), 256, 0, stream>>>(Wq, Wk, Wv, Wo, wbf);

    // batched Q/K/V projection with fused fp32->bf16 A conversion
    gemm_qkv<<<dim3(M / 128, DIM / 128, 3), 256, 0, stream>>>(
        query, keys, values, wbf, Qp, Kp, Vt);

    flash_attn<<<256, 512, 0, stream>>>(Qp, Kp, Vt, mask);

    gemm_out<<<dim3(M / 128, DIM / 128), 256, 0, stream>>>(
        Qp /*AO*/, wbf + 3 * DIM * DIM, out, bo);
}

// Round 6
// 728.085 us; speedup vs baseline: 1.4090x; 1.1141x over previous
//
#include <hip/hip_runtime.h>

typedef __bf16 bf16x8 __attribute__((ext_vector_type(8)));
typedef __bf16 bf16x4 __attribute__((ext_vector_type(4)));
typedef float f32x4 __attribute__((ext_vector_type(4)));
typedef float f32x16 __attribute__((ext_vector_type(16)));

#define MFMA16(a, b, c) __builtin_amdgcn_mfma_f32_16x16x32_bf16((a), (b), (c), 0, 0, 0)
#define MFMA32(a, b, c) __builtin_amdgcn_mfma_f32_32x32x16_bf16((a), (b), (c), 0, 0, 0)

static constexpr int SEQ = 4096;
static constexpr int DIM = 512;

typedef __attribute__((address_space(3))) void lds_void;
typedef __attribute__((address_space(1))) const void gbl_void;

__device__ __forceinline__ void glds16(const void* g, void* l) {
    __builtin_amdgcn_global_load_lds((gbl_void*)g, (lds_void*)l, 16, 0, 0);
}

__device__ __forceinline__ bf16x8 cvt8f(const float* __restrict__ p) {
    float4 f0 = *(const float4*)p;
    float4 f1 = *(const float4*)(p + 4);
    bf16x8 v;
    v[0] = (__bf16)f0.x; v[1] = (__bf16)f0.y; v[2] = (__bf16)f0.z; v[3] = (__bf16)f0.w;
    v[4] = (__bf16)f1.x; v[5] = (__bf16)f1.y; v[6] = (__bf16)f1.z; v[7] = (__bf16)f1.w;
    return v;
}

// ---------------------------------------------------------------------------
// Weight fp32 -> bf16 converter
// ---------------------------------------------------------------------------
__global__ __launch_bounds__(256)
void convert_w(const float* __restrict__ wq, const float* __restrict__ wk,
               const float* __restrict__ wv, const float* __restrict__ wo,
               __bf16* __restrict__ out)
{
    const int z = blockIdx.y;
    const float* src = (z == 0) ? wq : (z == 1) ? wk : (z == 2) ? wv : wo;
    __bf16* dst = out + (size_t)z * DIM * DIM;
    const int i = (blockIdx.x * 256 + threadIdx.x) * 8;
    *(bf16x8*)(dst + i) = cvt8f(src + i);
}

// ---------------------------------------------------------------------------
// Batched QKV projection GEMM (proven R3): z in {0,1,2} -> Qp, Kp, Vt^T.
// ---------------------------------------------------------------------------
__global__ __launch_bounds__(256, 3)
void gemm_qkv(const float* __restrict__ Aq, const float* __restrict__ Ak,
              const float* __restrict__ Av, const __bf16* __restrict__ Wb,
              __bf16* __restrict__ Qp, __bf16* __restrict__ Kp,
              __bf16* __restrict__ Vtp)
{
    const int z = blockIdx.z;
    const float* Ap = (z == 0) ? Aq : (z == 1) ? Ak : Av;
    const __bf16* Bp = Wb + (size_t)z * DIM * DIM;
    __bf16* Cp = (z == 0) ? Qp : (z == 1) ? Kp : Vtp;

    __shared__ __align__(16) char smem[128 * 132 * 2];   // 33792 B
    __bf16* As = (__bf16*)smem;                // [128][64]
    __bf16* Bs = (__bf16*)(smem + 16384);      // [128][64]

    const int tid  = threadIdx.x;
    const int wave = tid >> 6;
    const int lane = tid & 63;
    const int quad = lane >> 4;
    const int l16  = lane & 15;
    const int m0 = blockIdx.x * 128;
    const int n0 = blockIdx.y * 128;
    const int wm = (wave >> 1) * 64;
    const int wn = (wave & 1) * 64;

    f32x4 acc[4][4] = {};

    for (int k0 = 0; k0 < DIM; k0 += 64) {
        #pragma unroll
        for (int i = 0; i < 4; i++) {
            const int j = wave * 4 + i;
            const int t = j * 64 + lane;
            const int row = t >> 3, c8 = t & 7;
            glds16(Bp + (size_t)(n0 + row) * DIM + k0 + c8 * 8, &Bs[j * 512]);
            *(bf16x8*)&As[t * 8] =
                cvt8f(Ap + (size_t)(m0 + row) * DIM + k0 + c8 * 8);
        }
        __syncthreads();
        #pragma unroll
        for (int kk = 0; kk < 2; kk++) {
            bf16x8 af[4], bg[4];
            #pragma unroll
            for (int mt = 0; mt < 4; mt++)
                af[mt] = *(const bf16x8*)&As[(wm + mt * 16 + l16) * 64 + kk * 32 + quad * 8];
            #pragma unroll
            for (int nt = 0; nt < 4; nt++)
                bg[nt] = *(const bf16x8*)&Bs[(wn + nt * 16 + l16) * 64 + kk * 32 + quad * 8];
            #pragma unroll
            for (int mt = 0; mt < 4; mt++)
                #pragma unroll
                for (int nt = 0; nt < 4; nt++)
                    acc[mt][nt] = MFMA16(af[mt], bg[nt], acc[mt][nt]);
        }
        __syncthreads();
    }

    if (z < 2) {
        #pragma unroll
        for (int mt = 0; mt < 4; mt++)
            #pragma unroll
            for (int nt = 0; nt < 4; nt++)
                #pragma unroll
                for (int r = 0; r < 4; r++)
                    Cp[(size_t)(m0 + wm + mt * 16 + quad * 4 + r) * DIM
                       + n0 + wn + nt * 16 + l16] = (__bf16)acc[mt][nt][r];
    } else {
        // transpose epilogue: Vt[nb][d][s]
        __bf16* Tt = (__bf16*)smem;            // [128][132]
        __syncthreads();
        #pragma unroll
        for (int mt = 0; mt < 4; mt++)
            #pragma unroll
            for (int nt = 0; nt < 4; nt++)
                #pragma unroll
                for (int r = 0; r < 4; r++)
                    Tt[(wm + mt * 16 + quad * 4 + r) * 132 + wn + nt * 16 + l16]
                        = (__bf16)acc[mt][nt][r];
        __syncthreads();
        const int nb  = m0 >> 12;
        const int s0m = m0 & 4095;
        const int d   = tid >> 1;
        const int sh  = (tid & 1) * 64;
        __bf16* dst = Cp + (size_t)nb * DIM * SEQ + (size_t)(n0 + d) * SEQ + s0m + sh;
        #pragma unroll
        for (int i = 0; i < 8; i++) {
            bf16x8 vv;
            #pragma unroll
            for (int e = 0; e < 8; e++) vv[e] = Tt[(sh + i * 8 + e) * 132 + d];
            *(bf16x8*)(dst + i * 8) = vv;
        }
    }
}

// ---------------------------------------------------------------------------
// Output GEMM: C(fp32) = A(bf16) @ Wo(bf16)^T + bias (m97 structure)
// ---------------------------------------------------------------------------
__global__ __launch_bounds__(256, 3)
void gemm_out(const __bf16* __restrict__ Ap, const __bf16* __restrict__ Bp,
              float* __restrict__ Cp, const float* __restrict__ bias)
{
    __shared__ __align__(16) __bf16 As[128 * 64];
    __shared__ __align__(16) __bf16 Bs[128 * 64];
    const int tid  = threadIdx.x;
    const int wave = tid >> 6;
    const int lane = tid & 63;
    const int quad = lane >> 4;
    const int l16  = lane & 15;
    const int m0 = blockIdx.x * 128;
    const int n0 = blockIdx.y * 128;
    const int wm = (wave >> 1) * 64;
    const int wn = (wave & 1) * 64;

    f32x4 acc[4][4] = {};

    for (int k0 = 0; k0 < DIM; k0 += 64) {
        #pragma unroll
        for (int i = 0; i < 4; i++) {
            const int j = wave * 4 + i;
            const int c = j * 64 + lane;
            const int row = c >> 3, c8 = c & 7;
            glds16(Ap + (size_t)(m0 + row) * DIM + k0 + c8 * 8, &As[j * 512]);
            glds16(Bp + (size_t)(n0 + row) * DIM + k0 + c8 * 8, &Bs[j * 512]);
        }
        __syncthreads();
        #pragma unroll
        for (int kk = 0; kk < 2; kk++) {
            bf16x8 af[4], bg[4];
            #pragma unroll
            for (int mt = 0; mt < 4; mt++)
                af[mt] = *(const bf16x8*)&As[(wm + mt * 16 + l16) * 64 + kk * 32 + quad * 8];
            #pragma unroll
            for (int nt = 0; nt < 4; nt++)
                bg[nt] = *(const bf16x8*)&Bs[(wn + nt * 16 + l16) * 64 + kk * 32 + quad * 8];
            #pragma unroll
            for (int mt = 0; mt < 4; mt++)
                #pragma unroll
                for (int nt = 0; nt < 4; nt++)
                    acc[mt][nt] = MFMA16(af[mt], bg[nt], acc[mt][nt]);
        }
        __syncthreads();
    }
    #pragma unroll
    for (int mt = 0; mt < 4; mt++)
        #pragma unroll
        for (int nt = 0; nt < 4; nt++)
            #pragma unroll
            for (int r = 0; r < 4; r++) {
                const int col = n0 + wn + nt * 16 + l16;
                Cp[(size_t)(m0 + wm + mt * 16 + quad * 4 + r) * DIM + col]
                    = acc[mt][nt][r] + bias[col];
            }
}

// ---------------------------------------------------------------------------
// Flash attention v12 — no K/V LDS staging. K and V A-fragments have ZERO
// intra-block reuse (each byte read by exactly one lane once), so they load
// global->register directly (4x dwordx4/lane/chunk, 1-deep named-reg
// prefetch). Only the x8-reused operands stay in LDS: Q (staged ONCE,
// pitch 520 B + row-hash XOR swizzle) and P. Barriers drop 17/j -> 3/j,
// all raw s_barrier + lgkmcnt(0) only (no vmcnt drain -> global loads
// pipeline freely across them). setprio(1) around MFMA clusters.
// LDS 103.5 KB, 1 block/CU.
// ---------------------------------------------------------------------------
#define MKC(v, r4) ((r4) == 0 ? (v).x : (r4) == 1 ? (v).y : (r4) == 2 ? (v).z : (v).w)
#define WAITLGKM() asm volatile("s_waitcnt lgkmcnt(0)" ::: "memory")
#define BARRIER()  asm volatile("s_barrier" ::: "memory")

__global__ __launch_bounds__(512, 1)
void flash_attn(__bf16* __restrict__ Qp, const __bf16* __restrict__ Kp,
                const __bf16* __restrict__ Vt, const int* __restrict__ mask)
{
    constexpr float SCALE = 0.044194173824159216f;   // 1/sqrt(512)
    constexpr int QPITCH = 520;                      // bf16 units (1040 B rows)

    __shared__ __bf16 Qs[64 * QPITCH];  // 66560 B, hash-swizzled 16B chunks
    __shared__ __bf16 P[64 * 256];      // 32 KB, swizzled
    __shared__ float pmax[8 * 66];
    __shared__ float psum[8 * 66];

    const int bid  = blockIdx.x;
    const int n    = bid & 3;            // batch -> XCD-local K/V
    const int q0   = (bid >> 2) * 64;
    const int tid  = threadIdx.x;
    const int w    = tid >> 6;
    const int lane = tid & 63;
    const int l32  = lane & 31;
    const int half = lane >> 5;

    const __bf16* Qb = Qp + (size_t)n * SEQ * DIM;
    const __bf16* Kb = Kp + (size_t)n * SEQ * DIM;
    const __bf16* Vb = Vt + (size_t)n * DIM * SEQ;
    const int*    Mb = mask + (size_t)n * SEQ * SEQ;
    __bf16*       AO = Qp + (size_t)n * SEQ * DIM;   // alias; rows consumed first

    // ---- stage Q ONCE. Row r at pitch 520; chunk hash = (r&7)^((r>>3)&7).
    #pragma unroll
    for (int i = 0; i < 8; i++) {
        const int r  = i * 8 + w;
        const int hr = (r & 7) ^ ((r >> 3) & 7);
        const int cs = (lane & 56) | ((lane & 7) ^ hr);
        glds16(Qb + (size_t)(q0 + r) * DIM + cs * 8, &Qs[r * QPITCH]);
    }

    // per-lane K/V row pointers (A-frag rows: K kc=32w+l32, V d=32w+l32)
    const __bf16* kPtr  = Kb + (size_t)(32 * w + l32) * DIM + half * 8;
    const __bf16* vPtr0 = Vb + (size_t)(32 * w + l32) * SEQ + half * 8;
    const __bf16* vPtr1 = vPtr0 + (size_t)256 * SEQ;

    // Q-read chunk permutations for this lane's two q-rows
    const int h0 = (l32 & 7) ^ ((l32 >> 3) & 7);
    const int h1 = h0 ^ 4;
    int q0off[4], q1off[4];                     // bf16 offset of chunk within dc-slab
    #pragma unroll
    for (int ks = 0; ks < 4; ks++) {
        q0off[ks] = ((2 * ks + half) ^ h0) * 8;
        q1off[ks] = ((2 * ks + half) ^ h1) * 8;
    }
    const int qrow0 = l32 * QPITCH;
    const int qrow1 = (32 + l32) * QPITCH;

    float m0 = -__builtin_inff(), m1 = -__builtin_inff();
    float l0 = 0.f, l1 = 0.f;
    f32x16 o00 = {}, o01 = {}, o10 = {}, o11 = {};   // [h][qh]
    f32x16 s0, s1;

    bf16x8 kA[4], kB[4], vA[4], vB[4];

#define LOADK(buf, dc_) { _Pragma("unroll") \
    for (int ks = 0; ks < 4; ks++) \
        buf[ks] = *(const bf16x8*)(kPtr + (dc_) * 64 + ks * 16); }

#define LOADV(buf, vc_) { const __bf16* vp_ = ((vc_) < 4) ? vPtr0 : vPtr1; \
    _Pragma("unroll") \
    for (int ks = 0; ks < 4; ks++) \
        buf[ks] = *(const bf16x8*)(vp_ + ((vc_) & 3) * 64 + ks * 16); }

#define QK8(buf, dc_) { __builtin_amdgcn_s_setprio(1); \
    _Pragma("unroll") \
    for (int ks = 0; ks < 4; ks++) { \
        bf16x8 b0 = *(const bf16x8*)&Qs[qrow0 + (dc_) * 64 + q0off[ks]]; \
        bf16x8 b1 = *(const bf16x8*)&Qs[qrow1 + (dc_) * 64 + q1off[ks]]; \
        s0 = MFMA32(buf[ks], b0, s0); \
        s1 = MFMA32(buf[ks], b1, s1); \
    } __builtin_amdgcn_s_setprio(0); }

#define PV8(buf, vc_) { __builtin_amdgcn_s_setprio(1); \
    _Pragma("unroll") \
    for (int ks = 0; ks < 4; ks++) { \
        const int ck = ((vc_) & 3) * 8 + 2 * ks + half; \
        const int cp = (ck & 24) | ((ck & 7) ^ (l32 & 7)); \
        bf16x8 b0 = *(const bf16x8*)&P[l32 * 256 + cp * 8]; \
        bf16x8 b1 = *(const bf16x8*)&P[(32 + l32) * 256 + cp * 8]; \
        if ((vc_) < 4) { o00 = MFMA32(buf[ks], b0, o00); o01 = MFMA32(buf[ks], b1, o01); } \
        else           { o10 = MFMA32(buf[ks], b0, o10); o11 = MFMA32(buf[ks], b1, o11); } \
    } __builtin_amdgcn_s_setprio(0); }

    __syncthreads();            // Q staged (plain: drains the glds16 vmcnt)
    LOADK(kA, 0);               // j=0, dc=0

    #pragma unroll 1
    for (int j = 0; j < 16; j++) {
        const int k0 = j * 256;

        // ---- mask in C-fragment layout: lane (w,l32,half) covers
        // kc = 32w + 8g + 4*half + r4 for q = l32 and q = 32+l32
        int4 mk0[4], mk1[4];
        {
            const int* mp0 = Mb + (size_t)(q0 + l32) * SEQ + k0 + 32 * w + 4 * half;
            const int* mp1 = mp0 + (size_t)32 * SEQ;
            #pragma unroll
            for (int g = 0; g < 4; g++) {
                mk0[g] = *(const int4*)(mp0 + 8 * g);
                mk1[g] = *(const int4*)(mp1 + 8 * g);
            }
        }

        // ---- phase 1: S^T scores. Barrier-free; 1-deep reg prefetch.
        s0 = (f32x16){}; s1 = (f32x16){};
        LOADK(kB, 1); QK8(kA, 0);
        LOADK(kA, 2); QK8(kB, 1);
        LOADK(kB, 3); QK8(kA, 2);
        LOADK(kA, 4); QK8(kB, 3);
        LOADK(kB, 5); QK8(kA, 4);
        LOADK(kA, 6); QK8(kB, 5);
        LOADK(kB, 7); QK8(kA, 6);
                      QK8(kB, 7);

        // ---- per-lane partial max over this wave's 32 kcols (raw scores)
        {
            float mx0 = s0[0], mx1 = s1[0];
            #pragma unroll
            for (int r = 1; r < 16; r++) { mx0 = fmaxf(mx0, s0[r]); mx1 = fmaxf(mx1, s1[r]); }
            mx0 = fmaxf(mx0, __shfl_xor(mx0, 32));
            mx1 = fmaxf(mx1, __shfl_xor(mx1, 32));
            if (half == 0) pmax[w * 66 + l32]      = mx0;
            else           pmax[w * 66 + 32 + l32] = mx1;
        }
        WAITLGKM();
        BARRIER();              // A: pmax visible

        LOADV(vA, 0);           // V prefetch rides over the softmax VALU

        // ---- combine max; per-lane softmax state
        float mp0v = pmax[l32], mp1v = pmax[32 + l32];
        #pragma unroll
        for (int w2 = 1; w2 < 8; w2++) {
            mp0v = fmaxf(mp0v, pmax[w2 * 66 + l32]);
            mp1v = fmaxf(mp1v, pmax[w2 * 66 + 32 + l32]);
        }
        const float mn0 = fmaxf(m0, mp0v * SCALE);
        const float mn1 = fmaxf(m1, mp1v * SCALE);
        const float a0 = __expf(m0 - mn0);
        const float a1 = __expf(m1 - mn1);
        m0 = mn0; m1 = mn1;
        #pragma unroll
        for (int r = 0; r < 16; r++) {
            o00[r] *= a0; o10[r] *= a0;
            o01[r] *= a1; o11[r] *= a1;
        }

        // ---- exp + register-mask + vectorized P write + partial lsum
        float ls0 = 0.f, ls1 = 0.f;
        #pragma unroll
        for (int g = 0; g < 4; g++) {
            bf16x4 pv0, pv1;
            #pragma unroll
            for (int r4 = 0; r4 < 4; r4++) {
                const int r = g * 4 + r4;
                float p0 = __expf(s0[r] * SCALE - mn0);
                float p1 = __expf(s1[r] * SCALE - mn1);
                p0 = MKC(mk0[g], r4) ? p0 : 0.f;
                p1 = MKC(mk1[g], r4) ? p1 : 0.f;
                ls0 += p0; ls1 += p1;
                pv0[r4] = (__bf16)p0;
                pv1[r4] = (__bf16)p1;
            }
            const int c  = 4 * w + g;                        // kcol chunk 0..31
            const int cp = (c & 24) | ((c & 7) ^ (l32 & 7));
            *(bf16x4*)&P[l32 * 256 + cp * 8 + 4 * half]        = pv0;
            *(bf16x4*)&P[(32 + l32) * 256 + cp * 8 + 4 * half] = pv1;
        }
        ls0 += __shfl_xor(ls0, 32);
        ls1 += __shfl_xor(ls1, 32);
        if (half == 0) psum[w * 66 + l32]      = ls0;
        else           psum[w * 66 + 32 + l32] = ls1;
        WAITLGKM();
        BARRIER();              // B: P + psum visible (vA loads stay in flight)

        {
            float ss0 = 0.f, ss1 = 0.f;
            #pragma unroll
            for (int w2 = 0; w2 < 8; w2++) {
                ss0 += psum[w2 * 66 + l32];
                ss1 += psum[w2 * 66 + 32 + l32];
            }
            l0 = l0 * a0 + ss0;
            l1 = l1 * a1 + ss1;
        }

        // ---- phase 3: PV. Barrier-free; 1-deep reg prefetch.
        LOADV(vB, 1); PV8(vA, 0);
        LOADV(vA, 2); PV8(vB, 1);
        LOADV(vB, 3); PV8(vA, 2);
        LOADV(vA, 4); PV8(vB, 3);
        LOADV(vB, 5); PV8(vA, 4);
        LOADV(vA, 6); PV8(vB, 5);
        LOADV(vB, 7); PV8(vA, 6);
                      PV8(vB, 7);

        // advance K/V pointers; prefetch next j's first K chunk
        kPtr  += 256 * DIM;
        vPtr0 += 256;
        vPtr1 += 256;
        if (j < 15) LOADK(kA, 0);
        WAITLGKM();
        BARRIER();              // C: P safe to rewrite next j (kA stays in flight)
    }

    // ---- epilogue: AO[q][d] = O^T[d][q] / l
    const float li0 = 1.f / l0, li1 = 1.f / l1;
    __bf16* ao0 = AO + (size_t)(q0 + l32) * DIM;
    __bf16* ao1 = AO + (size_t)(q0 + 32 + l32) * DIM;
    #pragma unroll
    for (int h = 0; h < 2; h++) {
        #pragma unroll
        for (int g = 0; g < 4; g++) {
            bf16x4 v00, v01;
            #pragma unroll
            for (int r4 = 0; r4 < 4; r4++) {
                const int r = g * 4 + r4;
                v00[r4] = (__bf16)((h ? o10[r] : o00[r]) * li0);
                v01[r4] = (__bf16)((h ? o11[r] : o01[r]) * li1);
            }
            const int d = h * 256 + 32 * w + g * 8 + 4 * half;
            *(bf16x4*)&ao0[d] = v00;
            *(bf16x4*)&ao1[d] = v01;
        }
    }
#undef LOADK
#undef LOADV
#undef QK8
#undef PV8
}

// ---------------------------------------------------------------------------
extern "C" void kernel_launch(void* const* d_in, const int* in_sizes, int n_in,
                              void* d_out, int out_size, void* d_ws, size_t ws_size,
                              hipStream_t stream)
{
    const float* values = (const float*)d_in[0];
    const float* keys   = (const float*)d_in[1];
    const float* query  = (const float*)d_in[2];
    const int*   mask   = (const int*)d_in[3];
    const float* Wv = (const float*)d_in[4];
    const float* Wk = (const float*)d_in[5];
    const float* Wq = (const float*)d_in[6];
    const float* Wo = (const float*)d_in[7];
    const float* bo = (const float*)d_in[8];
    float* out = (float*)d_out;

    char* ws = (char*)d_ws;
    __bf16* Qp  = (__bf16*)(ws);                 // 16 MiB (AO aliases)
    __bf16* Kp  = (__bf16*)(ws + (16u << 20));   // 16 MiB
    __bf16* Vt  = (__bf16*)(ws + (32u << 20));   // 16 MiB
    __bf16* wbf = (__bf16*)(ws + (48u << 20));   // 2 MiB

    const int M = 4 * SEQ;  // 16384

    convert_w<<<dim3(128, 4), 256, 0, stream>>>(Wq, Wk, Wv, Wo, wbf);

    // batched Q/K/V projection with fused fp32->bf16 A conversion
    gemm_qkv<<<dim3(M / 128, DIM / 128, 3), 256, 0, stream>>>(
        query, keys, values, wbf, Qp, Kp, Vt);

    flash_attn<<<256, 512, 0, stream>>>(Qp, Kp, Vt, mask);

    gemm_out<<<dim3(M / 128, DIM / 128), 256, 0, stream>>>(
        Qp /*AO*/, wbf + 3 * DIM * DIM, out, bo);
}

// Round 7
// 724.228 us; speedup vs baseline: 1.4165x; 1.0053x over previous
//
#include <hip/hip_runtime.h>

typedef __bf16 bf16x8 __attribute__((ext_vector_type(8)));
typedef __bf16 bf16x4 __attribute__((ext_vector_type(4)));
typedef float f32x4 __attribute__((ext_vector_type(4)));
typedef float f32x16 __attribute__((ext_vector_type(16)));

#define MFMA16(a, b, c) __builtin_amdgcn_mfma_f32_16x16x32_bf16((a), (b), (c), 0, 0, 0)
#define MFMA32(a, b, c) __builtin_amdgcn_mfma_f32_32x32x16_bf16((a), (b), (c), 0, 0, 0)

static constexpr int SEQ = 4096;
static constexpr int DIM = 512;

typedef __attribute__((address_space(3))) void lds_void;
typedef __attribute__((address_space(1))) const void gbl_void;

__device__ __forceinline__ void glds16(const void* g, void* l) {
    __builtin_amdgcn_global_load_lds((gbl_void*)g, (lds_void*)l, 16, 0, 0);
}

__device__ __forceinline__ bf16x8 cvt8f(const float* __restrict__ p) {
    float4 f0 = *(const float4*)p;
    float4 f1 = *(const float4*)(p + 4);
    bf16x8 v;
    v[0] = (__bf16)f0.x; v[1] = (__bf16)f0.y; v[2] = (__bf16)f0.z; v[3] = (__bf16)f0.w;
    v[4] = (__bf16)f1.x; v[5] = (__bf16)f1.y; v[6] = (__bf16)f1.z; v[7] = (__bf16)f1.w;
    return v;
}

// ---------------------------------------------------------------------------
// Weight fp32 -> bf16 converter
// ---------------------------------------------------------------------------
__global__ __launch_bounds__(256)
void convert_w(const float* __restrict__ wq, const float* __restrict__ wk,
               const float* __restrict__ wv, const float* __restrict__ wo,
               __bf16* __restrict__ out)
{
    const int z = blockIdx.y;
    const float* src = (z == 0) ? wq : (z == 1) ? wk : (z == 2) ? wv : wo;
    __bf16* dst = out + (size_t)z * DIM * DIM;
    const int i = (blockIdx.x * 256 + threadIdx.x) * 8;
    *(bf16x8*)(dst + i) = cvt8f(src + i);
}

// ---------------------------------------------------------------------------
// Batched QKV projection GEMM (proven R3): z in {0,1,2} -> Qp, Kp, Vt^T.
// ---------------------------------------------------------------------------
__global__ __launch_bounds__(256, 3)
void gemm_qkv(const float* __restrict__ Aq, const float* __restrict__ Ak,
              const float* __restrict__ Av, const __bf16* __restrict__ Wb,
              __bf16* __restrict__ Qp, __bf16* __restrict__ Kp,
              __bf16* __restrict__ Vtp)
{
    const int z = blockIdx.z;
    const float* Ap = (z == 0) ? Aq : (z == 1) ? Ak : Av;
    const __bf16* Bp = Wb + (size_t)z * DIM * DIM;
    __bf16* Cp = (z == 0) ? Qp : (z == 1) ? Kp : Vtp;

    __shared__ __align__(16) char smem[128 * 132 * 2];   // 33792 B
    __bf16* As = (__bf16*)smem;                // [128][64]
    __bf16* Bs = (__bf16*)(smem + 16384);      // [128][64]

    const int tid  = threadIdx.x;
    const int wave = tid >> 6;
    const int lane = tid & 63;
    const int quad = lane >> 4;
    const int l16  = lane & 15;
    const int m0 = blockIdx.x * 128;
    const int n0 = blockIdx.y * 128;
    const int wm = (wave >> 1) * 64;
    const int wn = (wave & 1) * 64;

    f32x4 acc[4][4] = {};

    for (int k0 = 0; k0 < DIM; k0 += 64) {
        #pragma unroll
        for (int i = 0; i < 4; i++) {
            const int j = wave * 4 + i;
            const int t = j * 64 + lane;
            const int row = t >> 3, c8 = t & 7;
            glds16(Bp + (size_t)(n0 + row) * DIM + k0 + c8 * 8, &Bs[j * 512]);
            *(bf16x8*)&As[t * 8] =
                cvt8f(Ap + (size_t)(m0 + row) * DIM + k0 + c8 * 8);
        }
        __syncthreads();
        #pragma unroll
        for (int kk = 0; kk < 2; kk++) {
            bf16x8 af[4], bg[4];
            #pragma unroll
            for (int mt = 0; mt < 4; mt++)
                af[mt] = *(const bf16x8*)&As[(wm + mt * 16 + l16) * 64 + kk * 32 + quad * 8];
            #pragma unroll
            for (int nt = 0; nt < 4; nt++)
                bg[nt] = *(const bf16x8*)&Bs[(wn + nt * 16 + l16) * 64 + kk * 32 + quad * 8];
            #pragma unroll
            for (int mt = 0; mt < 4; mt++)
                #pragma unroll
                for (int nt = 0; nt < 4; nt++)
                    acc[mt][nt] = MFMA16(af[mt], bg[nt], acc[mt][nt]);
        }
        __syncthreads();
    }

    if (z < 2) {
        #pragma unroll
        for (int mt = 0; mt < 4; mt++)
            #pragma unroll
            for (int nt = 0; nt < 4; nt++)
                #pragma unroll
                for (int r = 0; r < 4; r++)
                    Cp[(size_t)(m0 + wm + mt * 16 + quad * 4 + r) * DIM
                       + n0 + wn + nt * 16 + l16] = (__bf16)acc[mt][nt][r];
    } else {
        // transpose epilogue: Vt[nb][d][s]
        __bf16* Tt = (__bf16*)smem;            // [128][132]
        __syncthreads();
        #pragma unroll
        for (int mt = 0; mt < 4; mt++)
            #pragma unroll
            for (int nt = 0; nt < 4; nt++)
                #pragma unroll
                for (int r = 0; r < 4; r++)
                    Tt[(wm + mt * 16 + quad * 4 + r) * 132 + wn + nt * 16 + l16]
                        = (__bf16)acc[mt][nt][r];
        __syncthreads();
        const int nb  = m0 >> 12;
        const int s0m = m0 & 4095;
        const int d   = tid >> 1;
        const int sh  = (tid & 1) * 64;
        __bf16* dst = Cp + (size_t)nb * DIM * SEQ + (size_t)(n0 + d) * SEQ + s0m + sh;
        #pragma unroll
        for (int i = 0; i < 8; i++) {
            bf16x8 vv;
            #pragma unroll
            for (int e = 0; e < 8; e++) vv[e] = Tt[(sh + i * 8 + e) * 132 + d];
            *(bf16x8*)(dst + i * 8) = vv;
        }
    }
}

// ---------------------------------------------------------------------------
// Output GEMM: C(fp32) = A(bf16) @ Wo(bf16)^T + bias (m97 structure)
// ---------------------------------------------------------------------------
__global__ __launch_bounds__(256, 3)
void gemm_out(const __bf16* __restrict__ Ap, const __bf16* __restrict__ Bp,
              float* __restrict__ Cp, const float* __restrict__ bias)
{
    __shared__ __align__(16) __bf16 As[128 * 64];
    __shared__ __align__(16) __bf16 Bs[128 * 64];
    const int tid  = threadIdx.x;
    const int wave = tid >> 6;
    const int lane = tid & 63;
    const int quad = lane >> 4;
    const int l16  = lane & 15;
    const int m0 = blockIdx.x * 128;
    const int n0 = blockIdx.y * 128;
    const int wm = (wave >> 1) * 64;
    const int wn = (wave & 1) * 64;

    f32x4 acc[4][4] = {};

    for (int k0 = 0; k0 < DIM; k0 += 64) {
        #pragma unroll
        for (int i = 0; i < 4; i++) {
            const int j = wave * 4 + i;
            const int c = j * 64 + lane;
            const int row = c >> 3, c8 = c & 7;
            glds16(Ap + (size_t)(m0 + row) * DIM + k0 + c8 * 8, &As[j * 512]);
            glds16(Bp + (size_t)(n0 + row) * DIM + k0 + c8 * 8, &Bs[j * 512]);
        }
        __syncthreads();
        #pragma unroll
        for (int kk = 0; kk < 2; kk++) {
            bf16x8 af[4], bg[4];
            #pragma unroll
            for (int mt = 0; mt < 4; mt++)
                af[mt] = *(const bf16x8*)&As[(wm + mt * 16 + l16) * 64 + kk * 32 + quad * 8];
            #pragma unroll
            for (int nt = 0; nt < 4; nt++)
                bg[nt] = *(const bf16x8*)&Bs[(wn + nt * 16 + l16) * 64 + kk * 32 + quad * 8];
            #pragma unroll
            for (int mt = 0; mt < 4; mt++)
                #pragma unroll
                for (int nt = 0; nt < 4; nt++)
                    acc[mt][nt] = MFMA16(af[mt], bg[nt], acc[mt][nt]);
        }
        __syncthreads();
    }
    #pragma unroll
    for (int mt = 0; mt < 4; mt++)
        #pragma unroll
        for (int nt = 0; nt < 4; nt++)
            #pragma unroll
            for (int r = 0; r < 4; r++) {
                const int col = n0 + wn + nt * 16 + l16;
                Cp[(size_t)(m0 + wm + mt * 16 + quad * 4 + r) * DIM + col]
                    = acc[mt][nt][r] + bias[col];
            }
}

// ---------------------------------------------------------------------------
// Flash attention v13 — v12 structure (K/V global->reg, Q/P in LDS, 3
// barriers/j) with two fixes from R6 counters:
// 1. Rotation pitches, NO XOR hashes: Qs pitch 520 (1040 B = 65 slots ≡ 1
//    mod 8) and P pitch 264 (528 B = 33 slots ≡ 1 mod 8) make lane reads
//    land at slot (l32 + chunk) mod 8 = free 2-way. R6's hash re-collided
//    lanes ON TOP of the pitch rotation (conflicts 3.46e7).
// 2. 2-deep K/V prefetch (3 named buffers each) + V chunks 0-2 issued at
//    K-phase tail: covers ~2 MFMA-clusters (~300 cy) of L2/L3 latency vs
//    1-deep's ~130 cy. WAR-safe: buffer reload follows its consumer MFMAs
//    in program order (in-order issue).
// LDS 104.8 KB, 1 block/CU.
// ---------------------------------------------------------------------------
#define MKC(v, r4) ((r4) == 0 ? (v).x : (r4) == 1 ? (v).y : (r4) == 2 ? (v).z : (v).w)
#define WAITLGKM() asm volatile("s_waitcnt lgkmcnt(0)" ::: "memory")
#define BARRIER()  asm volatile("s_barrier" ::: "memory")

__global__ __launch_bounds__(512, 1)
void flash_attn(__bf16* __restrict__ Qp, const __bf16* __restrict__ Kp,
                const __bf16* __restrict__ Vt, const int* __restrict__ mask)
{
    constexpr float SCALE = 0.044194173824159216f;   // 1/sqrt(512)
    constexpr int QPITCH = 520;                      // 1040 B rows: 65 slots = 1 mod 8
    constexpr int PPITCH = 264;                      // 528 B rows: 33 slots = 1 mod 8

    __shared__ __align__(16) __bf16 Qs[64 * QPITCH];  // 66560 B, linear rows
    __shared__ __align__(16) __bf16 P[64 * PPITCH];   // 33792 B, linear rows
    __shared__ float pmax[8 * 66];
    __shared__ float psum[8 * 66];

    const int bid  = blockIdx.x;
    const int n    = bid & 3;            // batch -> XCD-local K/V
    const int q0   = (bid >> 2) * 64;
    const int tid  = threadIdx.x;
    const int w    = tid >> 6;
    const int lane = tid & 63;
    const int l32  = lane & 31;
    const int half = lane >> 5;

    const __bf16* Qb = Qp + (size_t)n * SEQ * DIM;
    const __bf16* Kb = Kp + (size_t)n * SEQ * DIM;
    const __bf16* Vb = Vt + (size_t)n * DIM * SEQ;
    const int*    Mb = mask + (size_t)n * SEQ * SEQ;
    __bf16*       AO = Qp + (size_t)n * SEQ * DIM;   // alias; rows consumed first

    // ---- stage Q ONCE, fully linear (pitch rotation handles banks)
    #pragma unroll
    for (int i = 0; i < 8; i++) {
        const int r = i * 8 + w;
        glds16(Qb + (size_t)(q0 + r) * DIM + lane * 8, &Qs[r * QPITCH]);
    }

    // per-lane K/V row pointers (A-frag rows: K kc=32w+l32, V d=32w+l32)
    const __bf16* kPtr  = Kb + (size_t)(32 * w + l32) * DIM + half * 8;
    const __bf16* vPtr0 = Vb + (size_t)(32 * w + l32) * SEQ + half * 8;
    const __bf16* vPtr1 = vPtr0 + (size_t)256 * SEQ;

    const int qrow0 = l32 * QPITCH;
    const int qrow1 = (32 + l32) * QPITCH;

    float m0 = -__builtin_inff(), m1 = -__builtin_inff();
    float l0 = 0.f, l1 = 0.f;
    f32x16 o00 = {}, o01 = {}, o10 = {}, o11 = {};   // [h][qh]
    f32x16 s0, s1;

    bf16x8 kA[4], kB[4], kC[4], vA[4], vB[4], vC[4];

#define LOADKB(buf, base, dc_) { _Pragma("unroll") \
    for (int ks = 0; ks < 4; ks++) \
        buf[ks] = *(const bf16x8*)((base) + (dc_) * 64 + ks * 16); }

#define LOADV(buf, vc_) { const __bf16* vp_ = ((vc_) < 4) ? vPtr0 : vPtr1; \
    _Pragma("unroll") \
    for (int ks = 0; ks < 4; ks++) \
        buf[ks] = *(const bf16x8*)(vp_ + ((vc_) & 3) * 64 + ks * 16); }

#define QK8(buf, dc_) { __builtin_amdgcn_s_setprio(1); \
    _Pragma("unroll") \
    for (int ks = 0; ks < 4; ks++) { \
        bf16x8 b0 = *(const bf16x8*)&Qs[qrow0 + (dc_) * 64 + (2 * ks + half) * 8]; \
        bf16x8 b1 = *(const bf16x8*)&Qs[qrow1 + (dc_) * 64 + (2 * ks + half) * 8]; \
        s0 = MFMA32(buf[ks], b0, s0); \
        s1 = MFMA32(buf[ks], b1, s1); \
    } __builtin_amdgcn_s_setprio(0); }

#define PV8(buf, vc_) { __builtin_amdgcn_s_setprio(1); \
    _Pragma("unroll") \
    for (int ks = 0; ks < 4; ks++) { \
        const int ck = ((vc_) & 3) * 8 + 2 * ks + half; \
        bf16x8 b0 = *(const bf16x8*)&P[l32 * PPITCH + ck * 8]; \
        bf16x8 b1 = *(const bf16x8*)&P[(32 + l32) * PPITCH + ck * 8]; \
        if ((vc_) < 4) { o00 = MFMA32(buf[ks], b0, o00); o01 = MFMA32(buf[ks], b1, o01); } \
        else           { o10 = MFMA32(buf[ks], b0, o10); o11 = MFMA32(buf[ks], b1, o11); } \
    } __builtin_amdgcn_s_setprio(0); }

    __syncthreads();            // Q staged (drains the glds16 vmcnt)
    LOADKB(kA, kPtr, 0);        // j=0 chunks 0,1
    LOADKB(kB, kPtr, 1);

    #pragma unroll 1
    for (int j = 0; j < 16; j++) {
        const int k0 = j * 256;

        // ---- mask in C-fragment layout
        int4 mk0[4], mk1[4];
        {
            const int* mp0 = Mb + (size_t)(q0 + l32) * SEQ + k0 + 32 * w + 4 * half;
            const int* mp1 = mp0 + (size_t)32 * SEQ;
            #pragma unroll
            for (int g = 0; g < 4; g++) {
                mk0[g] = *(const int4*)(mp0 + 8 * g);
                mk1[g] = *(const int4*)(mp1 + 8 * g);
            }
        }

        // ---- phase 1: S^T. 2-deep reg prefetch; V 0-2 issued at tail.
        s0 = (f32x16){}; s1 = (f32x16){};
        LOADKB(kC, kPtr, 2);
        QK8(kA, 0); LOADKB(kA, kPtr, 3);
        QK8(kB, 1); LOADKB(kB, kPtr, 4);
        QK8(kC, 2); LOADKB(kC, kPtr, 5);
        QK8(kA, 3); LOADKB(kA, kPtr, 6);
        QK8(kB, 4); LOADKB(kB, kPtr, 7);
        QK8(kC, 5); LOADV(vA, 0);
        QK8(kA, 6); LOADV(vB, 1);
        QK8(kB, 7); LOADV(vC, 2);

        // ---- per-lane partial max over this wave's 32 kcols (raw scores)
        {
            float mx0 = s0[0], mx1 = s1[0];
            #pragma unroll
            for (int r = 1; r < 16; r++) { mx0 = fmaxf(mx0, s0[r]); mx1 = fmaxf(mx1, s1[r]); }
            mx0 = fmaxf(mx0, __shfl_xor(mx0, 32));
            mx1 = fmaxf(mx1, __shfl_xor(mx1, 32));
            if (half == 0) pmax[w * 66 + l32]      = mx0;
            else           pmax[w * 66 + 32 + l32] = mx1;
        }
        WAITLGKM();
        BARRIER();              // A: pmax visible

        // ---- combine max; per-lane softmax state
        float mp0v = pmax[l32], mp1v = pmax[32 + l32];
        #pragma unroll
        for (int w2 = 1; w2 < 8; w2++) {
            mp0v = fmaxf(mp0v, pmax[w2 * 66 + l32]);
            mp1v = fmaxf(mp1v, pmax[w2 * 66 + 32 + l32]);
        }
        const float mn0 = fmaxf(m0, mp0v * SCALE);
        const float mn1 = fmaxf(m1, mp1v * SCALE);
        const float a0 = __expf(m0 - mn0);
        const float a1 = __expf(m1 - mn1);
        m0 = mn0; m1 = mn1;
        #pragma unroll
        for (int r = 0; r < 16; r++) {
            o00[r] *= a0; o10[r] *= a0;
            o01[r] *= a1; o11[r] *= a1;
        }

        // ---- exp + register-mask + vectorized P write + partial lsum
        float ls0 = 0.f, ls1 = 0.f;
        #pragma unroll
        for (int g = 0; g < 4; g++) {
            bf16x4 pv0, pv1;
            #pragma unroll
            for (int r4 = 0; r4 < 4; r4++) {
                const int r = g * 4 + r4;
                float p0 = __expf(s0[r] * SCALE - mn0);
                float p1 = __expf(s1[r] * SCALE - mn1);
                p0 = MKC(mk0[g], r4) ? p0 : 0.f;
                p1 = MKC(mk1[g], r4) ? p1 : 0.f;
                ls0 += p0; ls1 += p1;
                pv0[r4] = (__bf16)p0;
                pv1[r4] = (__bf16)p1;
            }
            const int c = 4 * w + g;                         // kcol chunk 0..31
            *(bf16x4*)&P[l32 * PPITCH + c * 8 + 4 * half]        = pv0;
            *(bf16x4*)&P[(32 + l32) * PPITCH + c * 8 + 4 * half] = pv1;
        }
        ls0 += __shfl_xor(ls0, 32);
        ls1 += __shfl_xor(ls1, 32);
        if (half == 0) psum[w * 66 + l32]      = ls0;
        else           psum[w * 66 + 32 + l32] = ls1;
        WAITLGKM();
        BARRIER();              // B: P + psum visible (V loads stay in flight)

        {
            float ss0 = 0.f, ss1 = 0.f;
            #pragma unroll
            for (int w2 = 0; w2 < 8; w2++) {
                ss0 += psum[w2 * 66 + l32];
                ss1 += psum[w2 * 66 + 32 + l32];
            }
            l0 = l0 * a0 + ss0;
            l1 = l1 * a1 + ss1;
        }

        // ---- phase 3: PV. 2-deep; next-j K chunks 0,1 issued at tail.
        PV8(vA, 0); LOADV(vA, 3);
        PV8(vB, 1); LOADV(vB, 4);
        PV8(vC, 2); LOADV(vC, 5);
        PV8(vA, 3); LOADV(vA, 6);
        PV8(vB, 4); LOADV(vB, 7);
        PV8(vC, 5); if (j < 15) LOADKB(kA, kPtr + 256 * DIM, 0);
        PV8(vA, 6); if (j < 15) LOADKB(kB, kPtr + 256 * DIM, 1);
        PV8(vB, 7);

        kPtr  += 256 * DIM;
        vPtr0 += 256;
        vPtr1 += 256;
        WAITLGKM();
        BARRIER();              // C: P safe to rewrite next j (K loads in flight)
    }

    // ---- epilogue: AO[q][d] = O^T[d][q] / l
    const float li0 = 1.f / l0, li1 = 1.f / l1;
    __bf16* ao0 = AO + (size_t)(q0 + l32) * DIM;
    __bf16* ao1 = AO + (size_t)(q0 + 32 + l32) * DIM;
    #pragma unroll
    for (int h = 0; h < 2; h++) {
        #pragma unroll
        for (int g = 0; g < 4; g++) {
            bf16x4 v00, v01;
            #pragma unroll
            for (int r4 = 0; r4 < 4; r4++) {
                const int r = g * 4 + r4;
                v00[r4] = (__bf16)((h ? o10[r] : o00[r]) * li0);
                v01[r4] = (__bf16)((h ? o11[r] : o01[r]) * li1);
            }
            const int d = h * 256 + 32 * w + g * 8 + 4 * half;
            *(bf16x4*)&ao0[d] = v00;
            *(bf16x4*)&ao1[d] = v01;
        }
    }
#undef LOADKB
#undef LOADV
#undef QK8
#undef PV8
}

// ---------------------------------------------------------------------------
extern "C" void kernel_launch(void* const* d_in, const int* in_sizes, int n_in,
                              void* d_out, int out_size, void* d_ws, size_t ws_size,
                              hipStream_t stream)
{
    const float* values = (const float*)d_in[0];
    const float* keys   = (const float*)d_in[1];
    const float* query  = (const float*)d_in[2];
    const int*   mask   = (const int*)d_in[3];
    const float* Wv = (const float*)d_in[4];
    const float* Wk = (const float*)d_in[5];
    const float* Wq = (const float*)d_in[6];
    const float* Wo = (const float*)d_in[7];
    const float* bo = (const float*)d_in[8];
    float* out = (float*)d_out;

    char* ws = (char*)d_ws;
    __bf16* Qp  = (__bf16*)(ws);                 // 16 MiB (AO aliases)
    __bf16* Kp  = (__bf16*)(ws + (16u << 20));   // 16 MiB
    __bf16* Vt  = (__bf16*)(ws + (32u << 20));   // 16 MiB
    __bf16* wbf = (__bf16*)(ws + (48u << 20));   // 2 MiB

    const int M = 4 * SEQ;  // 16384

    convert_w<<<dim3(128, 4), 256, 0, stream>>>(Wq, Wk, Wv, Wo, wbf);

    // batched Q/K/V projection with fused fp32->bf16 A conversion
    gemm_qkv<<<dim3(M / 128, DIM / 128, 3), 256, 0, stream>>>(
        query, keys, values, wbf, Qp, Kp, Vt);

    flash_attn<<<256, 512, 0, stream>>>(Qp, Kp, Vt, mask);

    gemm_out<<<dim3(M / 128, DIM / 128), 256, 0, stream>>>(
        Qp /*AO*/, wbf + 3 * DIM * DIM, out, bo);
}